// Round 1
// baseline (205.665 us; speedup 1.0000x reference)
//
#include <hip/hip_runtime.h>
#include <math.h>

namespace {

constexpr int kB = 16384;
constexpr int kN = 12;
constexpr int kD = 64;
constexpr int kL = 2;
constexpr int kC = 4;
constexpr int kH = kN * kD;          // 768
constexpr float kEps = 1e-5f;

constexpr int WAVES_PER_BLOCK = 4;
constexpr int BLOCK = 64 * WAVES_PER_BLOCK;   // 256
constexpr int GRID = 1024;                    // 4096 waves -> 4 graphs/wave

__global__ __launch_bounds__(BLOCK, 2)
void gnn_fused(const float* __restrict__ x,
               const float* __restrict__ mp_w,
               const float* __restrict__ mp_b,
               const float* __restrict__ attn_w,
               const float* __restrict__ ln_g,
               const float* __restrict__ ln_b,
               const float* __restrict__ cls_w,
               const float* __restrict__ cls_b,
               float* __restrict__ out)
{
    // mp_w transposed: Wt[l][d][e] = mp_w[l][e][d]  (32 KB)
    __shared__ float Wt[kL][kD][kD];
    __shared__ float w2s[kL][kD];
    __shared__ float mpb[kL][kD];
    __shared__ float lng[kL][kD];
    __shared__ float lnb[kL][kD];
    // per-wave transposed h scratch: ht[wave][d][n]
    __shared__ float ht[WAVES_PER_BLOCK][kD][kN];

    const int tid = threadIdx.x;

    for (int i = tid; i < kL * kD * kD; i += BLOCK) {
        const int l = i >> 12;       // / (64*64)
        const int r = i & 4095;
        const int e = r >> 6;
        const int d = r & 63;
        Wt[l][d][e] = mp_w[i];
    }
    for (int i = tid; i < kL * kD; i += BLOCK) {
        const int l = i >> 6, d = i & 63;
        w2s[l][d] = attn_w[l * (2 * kD) + kD + d];  // second half = w2
        mpb[l][d] = mp_b[i];
        lng[l][d] = ln_g[i];
        lnb[l][d] = ln_b[i];
    }
    __syncthreads();

    const int lane = tid & 63;
    const int wid  = tid >> 6;
    const int gwave = blockIdx.x * WAVES_PER_BLOCK + wid;
    const int nwave = GRID * WAVES_PER_BLOCK;

    for (int b = gwave; b < kB; b += nwave) {
        // h[n] for this lane's feature d=lane
        float h[kN];
#pragma unroll
        for (int n = 0; n < kN; ++n)
            h[n] = x[b * kH + n * kD + lane];

#pragma unroll
        for (int l = 0; l < kL; ++l) {
            // ---- stage h transposed into LDS (lane d writes h[0..11][d]) ----
            float4* hrow = (float4*)(&ht[wid][lane][0]);
            hrow[0] = make_float4(h[0], h[1], h[2],  h[3]);
            hrow[1] = make_float4(h[4], h[5], h[6],  h[7]);
            hrow[2] = make_float4(h[8], h[9], h[10], h[11]);
            __builtin_amdgcn_wave_barrier();

            // ---- m[n] (this lane owns output column e=lane) ----
            float m[kN];
            const float bias = mpb[l][lane];
#pragma unroll
            for (int n = 0; n < kN; ++n) m[n] = bias;

#pragma unroll 16
            for (int d = 0; d < kD; ++d) {
                const float w = Wt[l][d][lane];
                const float4* hr = (const float4*)(&ht[wid][d][0]);
                const float4 a0 = hr[0];
                const float4 a1 = hr[1];
                const float4 a2 = hr[2];
                m[0]  = fmaf(a0.x, w, m[0]);
                m[1]  = fmaf(a0.y, w, m[1]);
                m[2]  = fmaf(a0.z, w, m[2]);
                m[3]  = fmaf(a0.w, w, m[3]);
                m[4]  = fmaf(a1.x, w, m[4]);
                m[5]  = fmaf(a1.y, w, m[5]);
                m[6]  = fmaf(a1.z, w, m[6]);
                m[7]  = fmaf(a1.w, w, m[7]);
                m[8]  = fmaf(a2.x, w, m[8]);
                m[9]  = fmaf(a2.y, w, m[9]);
                m[10] = fmaf(a2.z, w, m[10]);
                m[11] = fmaf(a2.w, w, m[11]);
            }
            __builtin_amdgcn_wave_barrier();

            // ---- ej[n] = sum_d h[n][d]*w2[d]; softmax over n (i-independent!) ----
            const float w2v = w2s[l][lane];
            float s[kN];
#pragma unroll
            for (int n = 0; n < kN; ++n) {
                float v = h[n] * w2v;
                v += __shfl_xor(v, 1);
                v += __shfl_xor(v, 2);
                v += __shfl_xor(v, 4);
                v += __shfl_xor(v, 8);
                v += __shfl_xor(v, 16);
                v += __shfl_xor(v, 32);
                s[n] = v;
            }
            float mx = s[0];
#pragma unroll
            for (int n = 1; n < kN; ++n) mx = fmaxf(mx, s[n]);
            float sum = 0.f;
#pragma unroll
            for (int n = 0; n < kN; ++n) {
                s[n] = __expf(s[n] - mx);
                sum += s[n];
            }
            const float inv = 1.f / sum;

            // agg vector (same for every node i): c = sum_j softmax_j * m[j]
            float c = 0.f;
#pragma unroll
            for (int n = 0; n < kN; ++n) c = fmaf(s[n], m[n], c);
            c *= inv;

            // ---- residual + exact GELU + LayerNorm ----
            const float g  = lng[l][lane];
            const float bb = lnb[l][lane];
#pragma unroll
            for (int n = 0; n < kN; ++n) {
                const float u  = h[n] + c;
                const float ge = 0.5f * u * (1.f + erff(u * 0.70710678118654752f));
                float s1 = ge;
                float s2 = ge * ge;
#pragma unroll
                for (int o = 1; o < 64; o <<= 1) {
                    s1 += __shfl_xor(s1, o);
                    s2 += __shfl_xor(s2, o);
                }
                const float mu  = s1 * (1.f / 64.f);
                const float var = s2 * (1.f / 64.f) - mu * mu;
                const float rs  = rsqrtf(var + kEps);
                h[n] = (ge - mu) * rs * g + bb;
            }
        }

        // ---- classifier: out[b][c] = sum_h hflat*cls_w[c] + cls_b ----
        float p0 = 0.f, p1 = 0.f, p2 = 0.f, p3 = 0.f;
#pragma unroll
        for (int n = 0; n < kN; ++n) {
            const float hv = h[n];
            const int base = n * kD + lane;
            p0 = fmaf(hv, cls_w[0 * kH + base], p0);
            p1 = fmaf(hv, cls_w[1 * kH + base], p1);
            p2 = fmaf(hv, cls_w[2 * kH + base], p2);
            p3 = fmaf(hv, cls_w[3 * kH + base], p3);
        }
#pragma unroll
        for (int o = 1; o < 64; o <<= 1) {
            p0 += __shfl_xor(p0, o);
            p1 += __shfl_xor(p1, o);
            p2 += __shfl_xor(p2, o);
            p3 += __shfl_xor(p3, o);
        }
        if (lane == 0) {
            out[b * kC + 0] = p0 + cls_b[0];
            out[b * kC + 1] = p1 + cls_b[1];
            out[b * kC + 2] = p2 + cls_b[2];
            out[b * kC + 3] = p3 + cls_b[3];
        }
    }
}

} // namespace

extern "C" void kernel_launch(void* const* d_in, const int* in_sizes, int n_in,
                              void* d_out, int out_size, void* d_ws, size_t ws_size,
                              hipStream_t stream)
{
    const float* x      = (const float*)d_in[0];
    const float* mp_w   = (const float*)d_in[1];
    const float* mp_b   = (const float*)d_in[2];
    const float* attn_w = (const float*)d_in[3];
    // d_in[4] = attn_b : scalar bias per layer -> cancels in softmax, unused
    const float* ln_g   = (const float*)d_in[5];
    const float* ln_b   = (const float*)d_in[6];
    const float* cls_w  = (const float*)d_in[7];
    const float* cls_b  = (const float*)d_in[8];
    float* out = (float*)d_out;

    gnn_fused<<<GRID, BLOCK, 0, stream>>>(x, mp_w, mp_b, attn_w,
                                          ln_g, ln_b, cls_w, cls_b, out);
}

// Round 2
// 73.518 us; speedup vs baseline: 2.7975x; 2.7975x over previous
//
#include <hip/hip_runtime.h>
#include <math.h>

namespace {

constexpr int kB = 16384;
constexpr int kN = 12;
constexpr int kD = 64;
constexpr int kL = 2;
constexpr int kH = kN * kD;          // 768
constexpr float kEps = 1e-5f;

constexpr int WAVES_PER_BLOCK = 4;
constexpr int BLOCK = 64 * WAVES_PER_BLOCK;   // 256
constexpr int GRID = 1024;                    // 4096 waves, 4 graphs/wave

// DPP move with old=0 / bound_ctrl=set-zero: invalid lanes contribute 0.
template<int ctrl, int rowmask, int bankmask>
__device__ __forceinline__ float dppmov0(float x) {
    int r = __builtin_amdgcn_update_dpp(0, __builtin_bit_cast(int, x),
                                        ctrl, rowmask, bankmask, true);
    return __builtin_bit_cast(float, r);
}

// Full-wave (64-lane) sum via DPP chain; result uniform (readlane 63).
__device__ __forceinline__ float waveSum(float x) {
    x += dppmov0<0x111, 0xF, 0xF>(x);   // row_shr:1
    x += dppmov0<0x112, 0xF, 0xF>(x);   // row_shr:2
    x += dppmov0<0x114, 0xF, 0xF>(x);   // row_shr:4
    x += dppmov0<0x118, 0xF, 0xF>(x);   // row_shr:8
    x += dppmov0<0x142, 0xA, 0xF>(x);   // row_bcast:15 -> rows 1,3
    x += dppmov0<0x143, 0xC, 0xF>(x);   // row_bcast:31 -> rows 2,3
    return __builtin_bit_cast(float,
        __builtin_amdgcn_readlane(__builtin_bit_cast(int, x), 63));
}

__global__ __launch_bounds__(BLOCK, 4)
void gnn_fused(const float* __restrict__ x,
               const float* __restrict__ mp_w,
               const float* __restrict__ mp_b,
               const float* __restrict__ attn_w,
               const float* __restrict__ ln_g,
               const float* __restrict__ ln_b,
               const float* __restrict__ cls_w,
               const float* __restrict__ cls_b,
               float* __restrict__ out)
{
    // Wt[l][d][e] = mp_w[l][e][d], padded leading dim (65) so both the
    // transpose staging writes and the hot-loop reads are conflict-free.
    __shared__ float Wt[kL][kD][kD + 1];
    __shared__ float w2s[kL][kD];
    __shared__ float mpb[kL][kD];
    __shared__ float lng[kL][kD];
    __shared__ float lnb[kL][kD];
    __shared__ float qlds[WAVES_PER_BLOCK][kD];

    const int tid = threadIdx.x;

    for (int i = tid; i < kL * kD * kD; i += BLOCK) {
        const int l = i >> 12;
        const int r = i & 4095;
        const int e = r >> 6;
        const int d = r & 63;
        Wt[l][d][e] = mp_w[i];          // coalesced read; stride-1 banks on write
    }
    for (int i = tid; i < kL * kD; i += BLOCK) {
        const int l = i >> 6, d = i & 63;
        w2s[l][d] = attn_w[l * (2 * kD) + kD + d];  // w2 half; w1 cancels in softmax
        mpb[l][d] = mp_b[i];
        lng[l][d] = ln_g[i];
        lnb[l][d] = ln_b[i];
    }
    __syncthreads();

    const int lane = tid & 63;
    const int wid  = tid >> 6;
    const int gwave = blockIdx.x * WAVES_PER_BLOCK + wid;
    const int nwave = GRID * WAVES_PER_BLOCK;

    for (int b = gwave; b < kB; b += nwave) {
        float h[kN];                    // lane owns feature d = lane
#pragma unroll
        for (int n = 0; n < kN; ++n)
            h[n] = x[b * kH + n * kD + lane];

#pragma unroll
        for (int l = 0; l < kL; ++l) {
            // ---- ej[n] = <h[n], w2>; softmax over n (i-independent) ----
            const float w2v = w2s[l][lane];
            float s[kN];
#pragma unroll
            for (int n = 0; n < kN; ++n)
                s[n] = waveSum(h[n] * w2v);

            float mx = s[0];
#pragma unroll
            for (int n = 1; n < kN; ++n) mx = fmaxf(mx, s[n]);
            float sum = 0.f;
#pragma unroll
            for (int n = 0; n < kN; ++n) {
                s[n] = __expf(s[n] - mx);
                sum += s[n];
            }
            const float inv = 1.f / sum;

            // ---- q[d] = inv * sum_n s[n]*h[n][d]  (per-lane, d = lane) ----
            float q = 0.f;
#pragma unroll
            for (int n = 0; n < kN; ++n) q = fmaf(s[n], h[n], q);
            q *= inv;
            qlds[wid][lane] = q;
            __builtin_amdgcn_wave_barrier();   // order write before reads below

            // ---- agg[e] = sum_d q[d]*W[e][d] + mp_b[e]  (lane owns e) ----
            float c = mpb[l][lane];
#pragma unroll
            for (int d4 = 0; d4 < kD / 4; ++d4) {
                const float4 qv = *(const float4*)&qlds[wid][d4 * 4];  // uniform bcast
                c = fmaf(qv.x, Wt[l][4 * d4 + 0][lane], c);
                c = fmaf(qv.y, Wt[l][4 * d4 + 1][lane], c);
                c = fmaf(qv.z, Wt[l][4 * d4 + 2][lane], c);
                c = fmaf(qv.w, Wt[l][4 * d4 + 3][lane], c);
            }

            // ---- residual + exact GELU + LayerNorm ----
            const float g  = lng[l][lane];
            const float bb = lnb[l][lane];
#pragma unroll
            for (int n = 0; n < kN; ++n) {
                const float u  = h[n] + c;
                const float ge = 0.5f * u * (1.f + erff(u * 0.70710678118654752f));
                const float s1 = waveSum(ge);
                const float s2 = waveSum(ge * ge);
                const float mu  = s1 * (1.f / 64.f);
                const float var = s2 * (1.f / 64.f) - mu * mu;
                const float rs  = rsqrtf(var + kEps);
                h[n] = (ge - mu) * rs * g + bb;
            }
        }

        // ---- classifier ----
        float p0 = 0.f, p1 = 0.f, p2 = 0.f, p3 = 0.f;
#pragma unroll
        for (int n = 0; n < kN; ++n) {
            const float hv = h[n];
            const int base = n * kD + lane;
            p0 = fmaf(hv, cls_w[0 * kH + base], p0);
            p1 = fmaf(hv, cls_w[1 * kH + base], p1);
            p2 = fmaf(hv, cls_w[2 * kH + base], p2);
            p3 = fmaf(hv, cls_w[3 * kH + base], p3);
        }
        p0 = waveSum(p0);
        p1 = waveSum(p1);
        p2 = waveSum(p2);
        p3 = waveSum(p3);
        if (lane == 0) {
            float4 o = make_float4(p0 + cls_b[0], p1 + cls_b[1],
                                   p2 + cls_b[2], p3 + cls_b[3]);
            *(float4*)&out[b * 4] = o;
        }
    }
}

} // namespace

extern "C" void kernel_launch(void* const* d_in, const int* in_sizes, int n_in,
                              void* d_out, int out_size, void* d_ws, size_t ws_size,
                              hipStream_t stream)
{
    const float* x      = (const float*)d_in[0];
    const float* mp_w   = (const float*)d_in[1];
    const float* mp_b   = (const float*)d_in[2];
    const float* attn_w = (const float*)d_in[3];
    // d_in[4] = attn_b : cancels in softmax, unused
    const float* ln_g   = (const float*)d_in[5];
    const float* ln_b   = (const float*)d_in[6];
    const float* cls_w  = (const float*)d_in[7];
    const float* cls_b  = (const float*)d_in[8];
    float* out = (float*)d_out;

    gnn_fused<<<GRID, BLOCK, 0, stream>>>(x, mp_w, mp_b, attn_w,
                                          ln_g, ln_b, cls_w, cls_b, out);
}

// Round 3
// 34.955 us; speedup vs baseline: 5.8837x; 2.1032x over previous
//
#include <hip/hip_runtime.h>
#include <math.h>

namespace {

constexpr int kB = 16384;
constexpr int kN = 12;
constexpr int kD = 64;
constexpr int kL = 2;
constexpr int kH = kN * kD;          // 768
constexpr float kEps = 1e-5f;

constexpr int WAVES_PER_BLOCK = 4;
constexpr int BLOCK = 64 * WAVES_PER_BLOCK;     // 256
constexpr int GRID  = kB / (4 * WAVES_PER_BLOCK); // 1024 -> 4 graphs/wave, 1 pass

// x += row_ror:N of x (within the 16-lane DPP row). All lanes valid.
template<int N>
__device__ __forceinline__ float dpp_ror_add(float x) {
    int r = __builtin_amdgcn_update_dpp(0, __builtin_bit_cast(int, x),
                                        0x120 + N, 0xF, 0xF, true);
    return x + __builtin_bit_cast(float, r);
}
// Sum over the 16-lane row; EVERY lane of the row ends with the total.
__device__ __forceinline__ float rowSum16(float x) {
    x = dpp_ror_add<8>(x);
    x = dpp_ror_add<4>(x);
    x = dpp_ror_add<2>(x);
    x = dpp_ror_add<1>(x);
    return x;
}

// tanh-form GELU: 0.5x(1+tanh(0.79788456(x+0.044715x^3))), tanh via exp+rcp.
// Max error vs exact erf-GELU ~1.5e-3; overflow-graceful (inf->x, -inf->0).
__device__ __forceinline__ float fast_gelu(float x) {
    const float x2 = x * x;
    const float y  = x * fmaf(x2, 0.0356774081f, 0.7978845608f);
    const float e  = __expf(2.0f * y);
    const float r  = __builtin_amdgcn_rcpf(e + 1.0f);
    const float t  = fmaf(-2.0f, r, 1.0f);      // tanh(y)
    const float hx = 0.5f * x;
    return fmaf(hx, t, hx);
}

__global__ __launch_bounds__(BLOCK, 4)
void gnn_fused(const float* __restrict__ x,
               const float* __restrict__ mp_w,
               const float* __restrict__ mp_b,
               const float* __restrict__ attn_w,
               const float* __restrict__ ln_g,
               const float* __restrict__ ln_b,
               const float* __restrict__ cls_w,
               const float* __restrict__ cls_b,
               float* __restrict__ out)
{
    // Wt[l][d][e ^ 4*(d&7)] = mp_w[l][e][d]  — XOR swizzle: conflict-free
    // float4 reads at any d, 8-way (one-time) on the transpose staging.
    __shared__ __align__(16) float Wt[kL][kD][kD];
    __shared__ __align__(16) float w2s[kL][kD];
    __shared__ __align__(16) float mpb[kL][kD];
    __shared__ __align__(16) float lng[kL][kD];
    __shared__ __align__(16) float lnb[kL][kD];
    __shared__ __align__(16) float qg[WAVES_PER_BLOCK][4][72]; // pitch 72: 16B-aligned rows, bank-shifted groups

    const int tid = threadIdx.x;

    for (int i = tid; i < kL * kD * kD; i += BLOCK) {
        const int l = i >> 12;
        const int r = i & 4095;
        const int e = r >> 6;
        const int d = r & 63;
        Wt[l][d][e ^ (4 * (d & 7))] = mp_w[i];   // coalesced global read
    }
    for (int i = tid; i < kL * kD; i += BLOCK) {
        const int l = i >> 6, d = i & 63;
        w2s[l][d] = attn_w[l * (2 * kD) + kD + d];  // w2 half; w1+attn_b cancel in softmax
        mpb[l][d] = mp_b[i];
        lng[l][d] = ln_g[i];
        lnb[l][d] = ln_b[i];
    }
    __syncthreads();

    const int lane = tid & 63;
    const int wid  = tid >> 6;
    const int grp  = lane >> 4;       // graph slot within wave (DPP row)
    const int sub  = lane & 15;       // lane within graph; owns d = 4*sub..4*sub+3

    const int b = (blockIdx.x * WAVES_PER_BLOCK + wid) * 4 + grp;

    // ---- load h: 12 nodes x 4 features per lane ----
    float4 h4[kN];
    const float* xb = x + b * kH + 4 * sub;
#pragma unroll
    for (int n = 0; n < kN; ++n)
        h4[n] = *(const float4*)(xb + n * kD);

#pragma unroll
    for (int l = 0; l < kL; ++l) {
        const float4 w2v = *(const float4*)&w2s[l][4 * sub];

        // ---- ej[n] = <h[n], w2> (16-lane reduce); softmax over n ----
        float s[kN];
#pragma unroll
        for (int n = 0; n < kN; ++n) {
            float v = h4[n].x * w2v.x;
            v = fmaf(h4[n].y, w2v.y, v);
            v = fmaf(h4[n].z, w2v.z, v);
            v = fmaf(h4[n].w, w2v.w, v);
            s[n] = rowSum16(v);
        }
        float mx = s[0];
#pragma unroll
        for (int n = 1; n < kN; ++n) mx = fmaxf(mx, s[n]);
        float sum = 0.f;
#pragma unroll
        for (int n = 0; n < kN; ++n) {
            s[n] = __expf(s[n] - mx);
            sum += s[n];
        }
        const float inv = __builtin_amdgcn_rcpf(sum);

        // ---- q[d] = sum_n s[n]*h[n][d] (unscaled; inv folded in later) ----
        float4 q = make_float4(0.f, 0.f, 0.f, 0.f);
#pragma unroll
        for (int n = 0; n < kN; ++n) {
            q.x = fmaf(s[n], h4[n].x, q.x);
            q.y = fmaf(s[n], h4[n].y, q.y);
            q.z = fmaf(s[n], h4[n].z, q.z);
            q.w = fmaf(s[n], h4[n].w, q.w);
        }
        *(float4*)&qg[wid][grp][4 * sub] = q;
        __builtin_amdgcn_wave_barrier();

        // ---- agg[e] = inv * sum_d q[d]*W[e][d] + mp_b[e]; lane owns e=4*sub+k ----
        float c0 = 0.f, c1 = 0.f, c2 = 0.f, c3 = 0.f;
        const float* qrow = &qg[wid][grp][0];
        const int e0 = 4 * sub;
#pragma unroll
        for (int d4 = 0; d4 < kD / 4; ++d4) {
            const float4 qv = *(const float4*)&qrow[4 * d4];
#pragma unroll
            for (int j = 0; j < 4; ++j) {
                const int d = 4 * d4 + j;
                const float4 wv = *(const float4*)&Wt[l][d][e0 ^ (4 * (d & 7))];
                const float qd = (j == 0) ? qv.x : (j == 1) ? qv.y : (j == 2) ? qv.z : qv.w;
                c0 = fmaf(qd, wv.x, c0);
                c1 = fmaf(qd, wv.y, c1);
                c2 = fmaf(qd, wv.z, c2);
                c3 = fmaf(qd, wv.w, c3);
            }
        }
        const float4 mb4 = *(const float4*)&mpb[l][4 * sub];
        const float4 cc = make_float4(fmaf(c0, inv, mb4.x), fmaf(c1, inv, mb4.y),
                                      fmaf(c2, inv, mb4.z), fmaf(c3, inv, mb4.w));

        // ---- residual + GELU + LayerNorm (per node, 64-feat = 16 lanes x 4) ----
        const float4 g4 = *(const float4*)&lng[l][4 * sub];
        const float4 b4 = *(const float4*)&lnb[l][4 * sub];
#pragma unroll
        for (int n = 0; n < kN; ++n) {
            const float ge0 = fast_gelu(h4[n].x + cc.x);
            const float ge1 = fast_gelu(h4[n].y + cc.y);
            const float ge2 = fast_gelu(h4[n].z + cc.z);
            const float ge3 = fast_gelu(h4[n].w + cc.w);
            float s1 = ge0 + ge1 + ge2 + ge3;
            float s2 = ge0 * ge0;
            s2 = fmaf(ge1, ge1, s2);
            s2 = fmaf(ge2, ge2, s2);
            s2 = fmaf(ge3, ge3, s2);
            s1 = rowSum16(s1);
            s2 = rowSum16(s2);
            const float mu  = s1 * (1.f / 64.f);
            const float var = fmaf(s2, 1.f / 64.f, -mu * mu);
            const float rs  = __builtin_amdgcn_rsqf(var + kEps);
            h4[n].x = fmaf(ge0 - mu, rs * g4.x, b4.x);
            h4[n].y = fmaf(ge1 - mu, rs * g4.y, b4.y);
            h4[n].z = fmaf(ge2 - mu, rs * g4.z, b4.z);
            h4[n].w = fmaf(ge3 - mu, rs * g4.w, b4.w);
        }
    }

    // ---- classifier: out[b][c] = sum h . cls_w[c] + cls_b ----
    float p[4] = {0.f, 0.f, 0.f, 0.f};
#pragma unroll
    for (int n = 0; n < kN; ++n) {
        const int base = n * kD + 4 * sub;
#pragma unroll
        for (int c = 0; c < 4; ++c) {
            const float4 cw = *(const float4*)(cls_w + c * kH + base);
            p[c] = fmaf(h4[n].x, cw.x, p[c]);
            p[c] = fmaf(h4[n].y, cw.y, p[c]);
            p[c] = fmaf(h4[n].z, cw.z, p[c]);
            p[c] = fmaf(h4[n].w, cw.w, p[c]);
        }
    }
#pragma unroll
    for (int c = 0; c < 4; ++c) p[c] = rowSum16(p[c]);

    if (sub == 0) {
        const float4 cb = *(const float4*)cls_b;
        *(float4*)&out[b * 4] = make_float4(p[0] + cb.x, p[1] + cb.y,
                                            p[2] + cb.z, p[3] + cb.w);
    }
}

} // namespace

extern "C" void kernel_launch(void* const* d_in, const int* in_sizes, int n_in,
                              void* d_out, int out_size, void* d_ws, size_t ws_size,
                              hipStream_t stream)
{
    const float* x      = (const float*)d_in[0];
    const float* mp_w   = (const float*)d_in[1];
    const float* mp_b   = (const float*)d_in[2];
    const float* attn_w = (const float*)d_in[3];
    // d_in[4] = attn_b : cancels in softmax, unused
    const float* ln_g   = (const float*)d_in[5];
    const float* ln_b   = (const float*)d_in[6];
    const float* cls_w  = (const float*)d_in[7];
    const float* cls_b  = (const float*)d_in[8];
    float* out = (float*)d_out;

    gnn_fused<<<GRID, BLOCK, 0, stream>>>(x, mp_w, mp_b, attn_w,
                                          ln_g, ln_b, cls_w, cls_b, out);
}